// Round 2
// baseline (1440.332 us; speedup 1.0000x reference)
//
#include <hip/hip_runtime.h>
#include <hip/hip_bf16.h>

static constexpr int H_ = 1024;
static constexpr int W_ = 1024;
static constexpr int STR_ = 16;
static constexpr int NH_ = 63;
static constexpr int NPATCH_ = NH_ * NH_;  // 3969

typedef short bf16x8 __attribute__((ext_vector_type(8)));
typedef short short4v __attribute__((ext_vector_type(4)));
typedef float f32x4 __attribute__((ext_vector_type(4)));

// ---------------------------------------------------------------------------
// LDS layout (bytes), total 83072 -> single 1024-thread block (16 waves/CU):
//   sH1: [0, 30000)         625 rows x 48B ([pixel][24ch bf16], NO pad --
//                           conv2 K-reads beyond 24ch hit next row: finite
//                           garbage x B-frag zeros (k>=24) = 0)
//   gap: [30000, 30016)     ZEROED in S0 -- the "next row" overread target of
//                           sH1 row 624 (S2 quad==3, S4b quad==3). Must be
//                           finite or NaN*0=NaN poisons valid outputs.
//   sH2: [30016, 83056)     442 rows x 120B ([pixel][60ch bf16]; row 441 = zero row)
//   patch copies overlay sH2 head (dead before conv2 writes):
//     copy0 [30016, 35136)  patch bf16 [2][32][40]
//     copy1 [35136, 40256)  same, shifted left 1 column
//   tail: [83056, 83072)    ZEROED in S0 -- zero-row quad==3 a1 overread
//                           (S3) lands here; same NaN*0 hazard.
//   After deconv2 (sH1/sH2 dead):
//     h3:  [0, 30000)       625 rows x 48B ([pixel][24ch bf16])
//     sWc: [30016, 34112)   64 rows x 64B (bf16 [r][32c], c>=24 zero)
//     sp:  [34112, 38208)   32x32 f32 accumulator
// ---------------------------------------------------------------------------
static constexpr int SH1_STRIDE = 48;
static constexpr int SH2_BASE   = 30016;
static constexpr int SH2_STRIDE = 120;
static constexpr int ZROW_REL   = 441 * SH2_STRIDE;   // 52920
static constexpr int SPB0       = 30016;
static constexpr int SPB1       = 35136;
static constexpr int SWC_BASE   = 30016;
static constexpr int SP_ACC     = 34112;
static constexpr int LDS_BYTES  = 83072;              // incl. 16B tail pad for zrow overread

__device__ __forceinline__ unsigned short f2bf(float x) {
    __hip_bfloat16 b = __float2bfloat16(x);
    return __builtin_bit_cast(unsigned short, b);
}

__device__ __forceinline__ f32x4 mfma_bf16(bf16x8 a, bf16x8 b, f32x4 c) {
    return __builtin_amdgcn_mfma_f32_16x16x32_bf16(a, b, c, 0, 0, 0);
}

__global__ __launch_bounds__(1024, 4) void fused_patch_kernel(
    const float* __restrict__ x1, const float* __restrict__ x2,
    const float* __restrict__ c1b, const float* __restrict__ c2b,
    const float* __restrict__ d2b, const float* __restrict__ d1b,
    const float* __restrict__ lin_w, const float* __restrict__ lin_b,
    const unsigned short* __restrict__ w1frag,   // conv1 B frags, bf16
    const unsigned short* __restrict__ w2frag,   // conv2 B frags, bf16
    const unsigned short* __restrict__ dw2frag,  // deconv2 B frags, bf16
    const float* __restrict__ dw1,               // raw deconv1_w (24,1,2,8,8)
    float* __restrict__ recon)                   // = d_out (atomic overlap-add)
{
    __shared__ alignas(16) char sbuf[LDS_BYTES];
    const int n  = blockIdx.x;
    const int t  = (int)threadIdx.x;
    const int pi = n / NH_, pj = n % NH_;
    const int Y0 = pi * STR_, X0 = pj * STR_;
    const int wv = t >> 6, lane = t & 63;
    const int ln15 = lane & 15, quad = lane >> 4;

    // ---- S0: zero zrow + both uninit overread windows; load patch f32 ->
    //          bf16, two parity copies ----
    if (t < 30)      ((float*)(sbuf + SH2_BASE + ZROW_REL))[t] = 0.f;       // zero row 441
    else if (t < 34) ((float*)(sbuf + 30000))[t - 30] = 0.f;                // sH1/sH2 gap
    else if (t < 38) ((float*)(sbuf + SH2_BASE + 53040))[t - 34] = 0.f;     // zrow tail pad
    for (int k = t; k < 2048; k += 1024) {
        int d = k >> 10, r = k & 1023, y = r >> 5, x = r & 31;
        unsigned short b = f2bf((d ? x2 : x1)[(Y0 + y) * W_ + (X0 + x)]);
        int row = (d * 32 + y) * 40;
        ((unsigned short*)(sbuf + SPB0))[row + x] = b;
        if (x > 0) ((unsigned short*)(sbuf + SPB1))[row + x - 1] = b;
    }
    __syncthreads();

    // ---- S1: conv1 as MFMA. M=800 (25 cols x 32 rows), N=32, K=128. 50 mtiles ----
    for (int tl = wv; tl < 50; tl += 16) {
        const int vcol = tl >> 1, ubase = (tl & 1) * 16;
        const int u = ubase + ln15;                 // may be >=25: junk row, discarded
        const char* abase = sbuf + ((vcol & 1) ? SPB1 : SPB0) + (vcol & ~1) * 2;
        f32x4 acc[2];
        acc[0] = (f32x4){0.f, 0.f, 0.f, 0.f};
        acc[1] = (f32x4){0.f, 0.f, 0.f, 0.f};
        #pragma unroll
        for (int kc = 0; kc < 4; ++kc) {
            const int idx8 = kc * 4 + quad;         // = k/8
            const int dd = idx8 >> 3, pp = idx8 & 7;
            const unsigned int* ap = (const unsigned int*)(abase + (dd * 32 + u + pp) * 80);
            union { unsigned int u4[4]; bf16x8 v; } af;
            af.u4[0] = ap[0]; af.u4[1] = ap[1]; af.u4[2] = ap[2]; af.u4[3] = ap[3];
            bf16x8 b0 = *(const bf16x8*)(w1frag + (((kc * 2 + 0) * 64) + lane) * 8);
            bf16x8 b1 = *(const bf16x8*)(w1frag + (((kc * 2 + 1) * 64) + lane) * 8);
            acc[0] = mfma_bf16(af.v, b0, acc[0]);
            acc[1] = mfma_bf16(af.v, b1, acc[1]);
        }
        #pragma unroll
        for (int ntp = 0; ntp < 2; ++ntp) {
            const int c = ntp * 16 + ln15;
            if (c < 24) {
                const float bias = c1b[c];
                #pragma unroll
                for (int r = 0; r < 4; ++r) {
                    int uu = ubase + quad * 4 + r;
                    if (uu < 25) {
                        float hv = acc[ntp][r] + bias;
                        hv = hv > 0.f ? hv : expm1f(hv);
                        *(unsigned short*)(sbuf + (uu * 25 + vcol) * SH1_STRIDE + c * 2) = f2bf(hv);
                    }
                }
            }
        }
    }
    __syncthreads();

    // ---- S2: conv2 as MFMA. M=441(->448, 28 mtiles), N=64 (60+4 pad), K=32
    //      (24 real ch + garbage x B-zeros). Waves 0..13: mtiles {wv, wv+14} ----
    if (wv < 14) {
        int abase2[2];
        #pragma unroll
        for (int i = 0; i < 2; ++i) {
            int m = (wv + i * 14) * 16 + ln15;
            if (m > 440) m = 440;            // M-pad: valid row, discarded on write
            abase2[i] = ((m / 21) * 25 + (m % 21)) * SH1_STRIDE;
        }
        float bias[4];
        #pragma unroll
        for (int nt = 0; nt < 4; ++nt) {
            int o = nt * 16 + ln15;
            bias[nt] = (o < 60) ? c2b[o] : 0.f;
        }
        f32x4 acc2[2][4];
        #pragma unroll
        for (int i = 0; i < 2; ++i)
            #pragma unroll
            for (int nt = 0; nt < 4; ++nt)
                acc2[i][nt] = (f32x4){0.f, 0.f, 0.f, 0.f};

        const unsigned short* wb = w2frag + lane * 8;
        #pragma unroll
        for (int p = 0; p < 5; ++p) {
            #pragma unroll
            for (int q = 0; q < 5; ++q) {
                const int tap  = p * 5 + q;
                const int toff = (p * 25 + q) * SH1_STRIDE;
                bf16x8 b[4];
                #pragma unroll
                for (int nt = 0; nt < 4; ++nt)
                    b[nt] = *(const bf16x8*)(wb + (tap * 4 + nt) * 512);
                #pragma unroll
                for (int i = 0; i < 2; ++i) {
                    bf16x8 a = *(const bf16x8*)(sbuf + abase2[i] + toff + quad * 16);  // b128
                    #pragma unroll
                    for (int nt = 0; nt < 4; ++nt)
                        acc2[i][nt] = mfma_bf16(a, b[nt], acc2[i][nt]);
                }
            }
        }
        // writeback: relu -> sH2 [pixel][60ch bf16]
        #pragma unroll
        for (int i = 0; i < 2; ++i) {
            #pragma unroll
            for (int r = 0; r < 4; ++r) {
                int pix = (wv + i * 14) * 16 + quad * 4 + r;
                if (pix < 441) {
                    unsigned short* rowp = (unsigned short*)(sbuf + SH2_BASE + pix * SH2_STRIDE);
                    #pragma unroll
                    for (int nt = 0; nt < 4; ++nt) {
                        int o = nt * 16 + ln15;
                        if (o < 60)
                            rowp[o] = f2bf(fmaxf(acc2[i][nt][r] + bias[nt], 0.f));
                    }
                }
            }
        }
    }
    __syncthreads();

    // ---- S3: deconv2 as MFMA. M=625(->640, 40 mtiles), N=32 (24+8 pad),
    //      K=64 (60+4 B-zero), 25 taps. Wave wv: mtiles {wv, wv+16, wv+32<40} ----
    f32x4 acc3[3][2];
    {
        #pragma unroll
        for (int i = 0; i < 3; ++i) {
            acc3[i][0] = (f32x4){0.f, 0.f, 0.f, 0.f};
            acc3[i][1] = (f32x4){0.f, 0.f, 0.f, 0.f};
        }
        int uarr[3], varr[3], a120[3];
        bool mval[3];
        #pragma unroll
        for (int i = 0; i < 3; ++i) {
            int m = (wv + i * 16) * 16 + ln15;
            mval[i] = (m < 625);
            int mc = mval[i] ? m : 0;
            uarr[i] = mc / 25; varr[i] = mc % 25;
            a120[i] = (uarr[i] * 21 + varr[i]) * SH2_STRIDE;
        }
        const unsigned short* db = dw2frag + lane * 8;
        #pragma unroll
        for (int dy = 0; dy < 5; ++dy) {
            #pragma unroll
            for (int dx = 0; dx < 5; ++dx) {
                const int tap   = dy * 5 + dx;
                const int t2off = (dy * 21 + dx) * SH2_STRIDE;
                bf16x8 b00 = *(const bf16x8*)(db + tap * 2048);
                bf16x8 b01 = *(const bf16x8*)(db + tap * 2048 + 512);
                bf16x8 b10 = *(const bf16x8*)(db + tap * 2048 + 1024);
                bf16x8 b11 = *(const bf16x8*)(db + tap * 2048 + 1536);
                #pragma unroll
                for (int i = 0; i < 3; ++i) {
                    if (i == 2 && wv >= 8) continue;       // wave-uniform skip
                    int yv = uarr[i] - dy, xv = varr[i] - dx;
                    bool ok = mval[i] && ((unsigned)yv < 21u) && ((unsigned)xv < 21u);
                    int ra = ok ? (a120[i] - t2off) : ZROW_REL;  // zero row -> +0
                    const char* ap = sbuf + SH2_BASE + ra + quad * 16;
                    short4v lo0 = *(const short4v*)(ap);          // ds_read_b64
                    short4v hi0 = *(const short4v*)(ap + 8);
                    bf16x8 a0 = __builtin_shufflevector(lo0, hi0, 0, 1, 2, 3, 4, 5, 6, 7);
                    acc3[i][0] = mfma_bf16(a0, b00, acc3[i][0]);
                    acc3[i][1] = mfma_bf16(a0, b01, acc3[i][1]);
                    short4v lo1 = *(const short4v*)(ap + 64);
                    short4v hi1 = *(const short4v*)(ap + 72);
                    bf16x8 a1 = __builtin_shufflevector(lo1, hi1, 0, 1, 2, 3, 4, 5, 6, 7);
                    acc3[i][0] = mfma_bf16(a1, b10, acc3[i][0]);
                    acc3[i][1] = mfma_bf16(a1, b11, acc3[i][1]);
                }
            }
        }
    }
    __syncthreads();   // sH1 & sH2 fully dead from here

    // ---- S4a: h3 = elu(acc3 + d2b) -> bf16 [625][24ch] stride 48B;
    //           build sWc (bf16, c>=24 zero); zero sp ----
    const float lw0 = lin_w[2 * n], lw1 = lin_w[2 * n + 1];
    float* sp = (float*)(sbuf + SP_ACC);
    {
        const int c0 = ln15, c1 = 16 + ln15;
        const float db0 = d2b[c0];
        const float db1 = (c1 < 24) ? d2b[c1] : 0.f;
        #pragma unroll
        for (int i = 0; i < 3; ++i) {
            if (i == 2 && wv >= 8) continue;
            #pragma unroll
            for (int r = 0; r < 4; ++r) {
                int pix = (wv + i * 16) * 16 + quad * 4 + r;
                if (pix < 625) {
                    unsigned short* rowp = (unsigned short*)(sbuf + pix * SH1_STRIDE);
                    float hv = acc3[i][0][r] + db0;
                    rowp[c0] = f2bf(hv > 0.f ? hv : expm1f(hv));
                    if (c1 < 24) {
                        float hw = acc3[i][1][r] + db1;
                        rowp[c1] = f2bf(hw > 0.f ? hw : expm1f(hw));
                    }
                }
            }
        }
    }
    for (int k = t; k < 2048; k += 1024) {   // sWc: 64 r x 32 c, stride 64B
        int r = k >> 5, c = k & 31;
        float v = 0.f;
        if (c < 24)
            v = lw0 * dw1[(c * 2 + 0) * 64 + r] + lw1 * dw1[(c * 2 + 1) * 64 + r];
        ((unsigned short*)(sbuf + SWC_BASE))[r * 32 + c] = f2bf(v);
    }
    sp[t] = 0.f;
    __syncthreads();

    // ---- S4b: epilogue GEMM p[pix][r] = sum_c h3[pix][c]*wc[r][c] (K=32),
    //           scatter-add into sp via LDS atomics ----
    {
        bf16x8 wbv[4];
        #pragma unroll
        for (int nt = 0; nt < 4; ++nt)
            wbv[nt] = *(const bf16x8*)(sbuf + SWC_BASE + (nt * 16 + ln15) * 64 + quad * 16);
        #pragma unroll
        for (int i = 0; i < 3; ++i) {
            int mt = wv + i * 16;
            if (mt >= 40) continue;                 // wave-uniform
            int m = mt * 16 + ln15;
            if (m > 624) m = 624;
            bf16x8 a = *(const bf16x8*)(sbuf + m * SH1_STRIDE + quad * 16);  // b128
            #pragma unroll
            for (int nt = 0; nt < 4; ++nt) {
                f32x4 acc4 = (f32x4){0.f, 0.f, 0.f, 0.f};
                acc4 = mfma_bf16(a, wbv[nt], acc4);
                #pragma unroll
                for (int r = 0; r < 4; ++r) {
                    int pix = mt * 16 + quad * 4 + r;
                    if (pix < 625) {
                        int u = pix / 25, v = pix % 25;
                        int rv = nt * 16 + ln15;
                        atomicAdd(&sp[(u + (rv >> 3)) * 32 + v + (rv & 7)], acc4[r]);
                    }
                }
            }
        }
    }
    __syncthreads();

    // ---- S5: overlap-add into global recon ----
    const float obias = d1b[0] * (lw0 + lw1) + lin_b[n];
    {
        int yy = t >> 5, xx = t & 31;
        atomicAdd(&recon[(Y0 + yy) * W_ + (X0 + xx)], sp[t] + obias);
    }
}

// ---------------------------------------------------------------------------
// Prep (layouts unchanged from R4):
//  conv1:   i = (kc*2+nt)*512 + lane*8 + j -> n=nt*16+(lane&15), k=kc*32+(lane>>4)*8+j
//  conv2:   tap*2048 + nt*512 + lane*8 + j -> o=nt*16+ln15, c=quad*8+j (zeros o>=60, c>=24)
//  deconv2: tap*2048 + kc*1024 + nt*512 + lane*8 + j -> k=kc*32+quad*8+j, c=nt*16+ln15
//           (zeros k>=60, c>=24)
// ---------------------------------------------------------------------------
__global__ void prep_kernel(const float* __restrict__ c1w,
                            const float* __restrict__ c2w,
                            const float* __restrict__ d2w,
                            unsigned short* __restrict__ w1frag,
                            unsigned short* __restrict__ w2frag,
                            unsigned short* __restrict__ dw2frag)
{
    int i = blockIdx.x * blockDim.x + threadIdx.x;
    if (i < 51200) {
        int j = i & 7, lane = (i >> 3) & 63;
        int ln15 = lane & 15, quad = lane >> 4;
        if (i < 4096) {   // conv1
            int g = i >> 9;                   // = kc*2 + nt
            int kc = g >> 1, nt = g & 1;
            int nn = nt * 16 + ln15, k = kc * 32 + quad * 8 + j;
            w1frag[i] = f2bf((nn < 24) ? c1w[nn * 128 + k] : 0.f);
        }
        {   // conv2
            int nt = (i >> 9) & 3, tap = i >> 11;
            int o = nt * 16 + ln15, c = quad * 8 + j;
            float v = (o < 60 && c < 24) ? c2w[(o * 24 + c) * 25 + tap] : 0.f;
            w2frag[i] = f2bf(v);
        }
        {   // deconv2
            int nt = (i >> 9) & 1, kc = (i >> 10) & 1, tap = i >> 11;
            int k = kc * 32 + quad * 8 + j, c = nt * 16 + ln15;
            float v = (k < 60 && c < 24) ? d2w[(k * 24 + c) * 25 + tap] : 0.f;
            dw2frag[i] = f2bf(v);
        }
    }
}

__global__ void finalize_kernel(const float* __restrict__ x2,
                                const float* __restrict__ l1w,
                                float* __restrict__ out)
{
    int i = blockIdx.x * blockDim.x + threadIdx.x;
    if (i < H_ * W_) {
        float r = out[i];
        out[i] = x2[i] - r * l1w[0];
    }
}

extern "C" void kernel_launch(void* const* d_in, const int* in_sizes, int n_in,
                              void* d_out, int out_size, void* d_ws, size_t ws_size,
                              hipStream_t stream)
{
    const float* x1  = (const float*)d_in[0];
    const float* x2  = (const float*)d_in[1];
    const float* c1w = (const float*)d_in[2];
    const float* c1b = (const float*)d_in[3];
    const float* c2w = (const float*)d_in[4];
    const float* c2b = (const float*)d_in[5];
    const float* d2w = (const float*)d_in[6];
    const float* d2b = (const float*)d_in[7];
    const float* d1w = (const float*)d_in[8];
    const float* d1b = (const float*)d_in[9];
    const float* lw  = (const float*)d_in[10];
    const float* lb  = (const float*)d_in[11];
    const float* l1w = (const float*)d_in[12];

    float*          out     = (float*)d_out;
    unsigned short* w1frag  = (unsigned short*)d_ws;                      // 8192 B
    unsigned short* w2frag  = (unsigned short*)((char*)d_ws + 8192);      // 102400 B
    unsigned short* dw2frag = (unsigned short*)((char*)d_ws + 110592);    // 102400 B

    hipMemsetAsync(d_out, 0, (size_t)H_ * W_ * sizeof(float), stream);
    prep_kernel<<<100, 512, 0, stream>>>(c1w, c2w, d2w, w1frag, w2frag, dw2frag);
    fused_patch_kernel<<<NPATCH_, 1024, 0, stream>>>(x1, x2, c1b, c2b, d2b, d1b,
                                                     lw, lb, w1frag, w2frag, dw2frag,
                                                     d1w, out);
    finalize_kernel<<<(H_ * W_ + 255) / 256, 256, 0, stream>>>(x2, l1w, out);
}

// Round 3
// 1384.623 us; speedup vs baseline: 1.0402x; 1.0402x over previous
//
#include <hip/hip_runtime.h>
#include <hip/hip_bf16.h>

static constexpr int H_ = 1024;
static constexpr int W_ = 1024;
static constexpr int STR_ = 16;
static constexpr int NH_ = 63;
static constexpr int NPATCH_ = NH_ * NH_;  // 3969

typedef short bf16x8 __attribute__((ext_vector_type(8)));
typedef short short4v __attribute__((ext_vector_type(4)));
typedef float f32x4 __attribute__((ext_vector_type(4)));

// ---------------------------------------------------------------------------
// LDS layout (bytes), total 83072 -> single 1024-thread block (16 waves/CU):
//   sH1: [0, 30000)         625 rows x 48B ([pixel][24ch bf16], NO pad --
//                           conv2 K-reads beyond 24ch hit next row: finite
//                           garbage x B-frag zeros (k>=24) = 0)
//   gap: [30000, 30016)     ZEROED in S0 -- the "next row" overread target of
//                           sH1 row 624 (S2 quad==3, S4b quad==3). Must be
//                           finite or NaN*0=NaN poisons valid outputs.
//   sH2: [30016, 83056)     442 rows x 120B ([pixel][60ch bf16]; row 441 = zero row)
//   patch copies overlay sH2 head (dead before conv2 writes):
//     copy0 [30016, 35136)  patch bf16 [2][32][40]
//     copy1 [35136, 40256)  same, shifted left 1 column
//   tail: [83056, 83072)    ZEROED in S0 -- zero-row quad==3 a1 overread
//                           (S3) lands here; same NaN*0 hazard.
//   After deconv2 (sH1/sH2 dead):
//     h3:  [0, 30000)       625 rows x 48B ([pixel][24ch bf16])
//     sWc: [30016, 34112)   64 rows x 64B (bf16 [r][32c], c>=24 zero)
//     sp:  [34112, 38208)   32x32 f32 accumulator
// ---------------------------------------------------------------------------
static constexpr int SH1_STRIDE = 48;
static constexpr int SH2_BASE   = 30016;
static constexpr int SH2_STRIDE = 120;
static constexpr int ZROW_REL   = 441 * SH2_STRIDE;   // 52920
static constexpr int SPB0       = 30016;
static constexpr int SPB1       = 35136;
static constexpr int SWC_BASE   = 30016;
static constexpr int SP_ACC     = 34112;
static constexpr int LDS_BYTES  = 83072;              // incl. 16B tail pad for zrow overread

__device__ __forceinline__ unsigned short f2bf(float x) {
    __hip_bfloat16 b = __float2bfloat16(x);
    return __builtin_bit_cast(unsigned short, b);
}

__device__ __forceinline__ f32x4 mfma_bf16(bf16x8 a, bf16x8 b, f32x4 c) {
    return __builtin_amdgcn_mfma_f32_16x16x32_bf16(a, b, c, 0, 0, 0);
}

// fast ELU negative branch: expm1f is ~20 VALU ops; __expf-1 is ~4 and the
// bf16 store (rel 2^-9) swamps the ulp difference.
__device__ __forceinline__ float elu_neg(float x) { return __expf(x) - 1.f; }

__global__ __launch_bounds__(1024, 4) void fused_patch_kernel(
    const float* __restrict__ x1, const float* __restrict__ x2,
    const float* __restrict__ c1b, const float* __restrict__ c2b,
    const float* __restrict__ d2b, const float* __restrict__ d1b,
    const float* __restrict__ lin_w, const float* __restrict__ lin_b,
    const unsigned short* __restrict__ w1frag,   // conv1 B frags, bf16
    const unsigned short* __restrict__ w2frag,   // conv2 B frags, bf16
    const unsigned short* __restrict__ dw2frag,  // deconv2 B frags, bf16
    const float* __restrict__ dw1,               // raw deconv1_w (24,1,2,8,8)
    float* __restrict__ recon)                   // = d_out (atomic overlap-add)
{
    __shared__ alignas(16) char sbuf[LDS_BYTES];
    const int n  = blockIdx.x;
    const int t  = (int)threadIdx.x;
    const int pi = n / NH_, pj = n % NH_;
    const int Y0 = pi * STR_, X0 = pj * STR_;
    const int wv = t >> 6, lane = t & 63;
    const int ln15 = lane & 15, quad = lane >> 4;

    // ---- Top preloads: issued before S0 so latency overlaps patch staging.
    //      (Previously these loaded inside their phases -> phase-start stalls.)
    bf16x8 w1b[8];                               // conv1 B frags, loop-invariant
    #pragma unroll
    for (int g = 0; g < 8; ++g)
        w1b[g] = *(const bf16x8*)(w1frag + (g * 64 + lane) * 8);
    const float lw0  = lin_w[2 * n], lw1 = lin_w[2 * n + 1];
    const float lbn  = lin_b[n];
    const float d1b0 = d1b[0];
    const float c1b0 = c1b[ln15];
    const float c1b1 = (16 + ln15 < 24) ? c1b[16 + ln15] : 0.f;
    float c2bias[4];
    #pragma unroll
    for (int nt = 0; nt < 4; ++nt) {
        int o = nt * 16 + ln15;
        c2bias[nt] = (o < 60) ? c2b[o] : 0.f;
    }
    const float db0 = d2b[ln15];
    const float db1 = (16 + ln15 < 24) ? d2b[16 + ln15] : 0.f;
    float dwp[4] = {0.f, 0.f, 0.f, 0.f};         // scattered dw1 gather for sWc
    {
        int r0 = t >> 5, c0 = t & 31;
        if (c0 < 24) {
            dwp[0] = dw1[(c0 * 2 + 0) * 64 + r0];
            dwp[1] = dw1[(c0 * 2 + 1) * 64 + r0];
        }
        int k1 = t + 1024, r1 = k1 >> 5, c1 = k1 & 31;
        if (c1 < 24) {
            dwp[2] = dw1[(c1 * 2 + 0) * 64 + r1];
            dwp[3] = dw1[(c1 * 2 + 1) * 64 + r1];
        }
    }

    // ---- S0: zero zrow + both uninit overread windows; load patch f32 ->
    //          bf16, two parity copies ----
    if (t < 30)      ((float*)(sbuf + SH2_BASE + ZROW_REL))[t] = 0.f;       // zero row 441
    else if (t < 34) ((float*)(sbuf + 30000))[t - 30] = 0.f;                // sH1/sH2 gap
    else if (t < 38) ((float*)(sbuf + SH2_BASE + 53040))[t - 34] = 0.f;     // zrow tail pad
    for (int k = t; k < 2048; k += 1024) {
        int d = k >> 10, r = k & 1023, y = r >> 5, x = r & 31;
        unsigned short b = f2bf((d ? x2 : x1)[(Y0 + y) * W_ + (X0 + x)]);
        int row = (d * 32 + y) * 40;
        ((unsigned short*)(sbuf + SPB0))[row + x] = b;
        if (x > 0) ((unsigned short*)(sbuf + SPB1))[row + x - 1] = b;
    }
    __syncthreads();

    // ---- S1: conv1 as MFMA. M=800 (25 cols x 32 rows), N=32, K=128. 50 mtiles.
    //      B frags preloaded in w1b[] (loop-invariant). ----
    for (int tl = wv; tl < 50; tl += 16) {
        const int vcol = tl >> 1, ubase = (tl & 1) * 16;
        const int u = ubase + ln15;                 // may be >=25: junk row, discarded
        const char* abase = sbuf + ((vcol & 1) ? SPB1 : SPB0) + (vcol & ~1) * 2;
        f32x4 acc[2];
        acc[0] = (f32x4){0.f, 0.f, 0.f, 0.f};
        acc[1] = (f32x4){0.f, 0.f, 0.f, 0.f};
        #pragma unroll
        for (int kc = 0; kc < 4; ++kc) {
            const int idx8 = kc * 4 + quad;         // = k/8
            const int dd = idx8 >> 3, pp = idx8 & 7;
            const unsigned int* ap = (const unsigned int*)(abase + (dd * 32 + u + pp) * 80);
            union { unsigned int u4[4]; bf16x8 v; } af;
            af.u4[0] = ap[0]; af.u4[1] = ap[1]; af.u4[2] = ap[2]; af.u4[3] = ap[3];
            acc[0] = mfma_bf16(af.v, w1b[kc * 2 + 0], acc[0]);
            acc[1] = mfma_bf16(af.v, w1b[kc * 2 + 1], acc[1]);
        }
        #pragma unroll
        for (int ntp = 0; ntp < 2; ++ntp) {
            const int c = ntp * 16 + ln15;
            if (c < 24) {
                const float bias = ntp ? c1b1 : c1b0;
                #pragma unroll
                for (int r = 0; r < 4; ++r) {
                    int uu = ubase + quad * 4 + r;
                    if (uu < 25) {
                        float hv = acc[ntp][r] + bias;
                        hv = hv > 0.f ? hv : elu_neg(hv);
                        *(unsigned short*)(sbuf + (uu * 25 + vcol) * SH1_STRIDE + c * 2) = f2bf(hv);
                    }
                }
            }
        }
    }
    __syncthreads();

    // ---- S2: conv2 as MFMA. M=441(->448, 28 mtiles), N=64 (60+4 pad), K=32
    //      (24 real ch + garbage x B-zeros). Waves 0..13: mtiles {wv, wv+14}.
    //      Depth-1 software pipeline: prefetch tap+1's B (global/L2) and A (LDS)
    //      while tap's 8 MFMAs issue -- hides ~300cyc L2 latency that the
    //      52-VGPR schedule serialized. ----
    if (wv < 14) {
        int abase2[2];
        #pragma unroll
        for (int i = 0; i < 2; ++i) {
            int m = (wv + i * 14) * 16 + ln15;
            if (m > 440) m = 440;            // M-pad: valid row, discarded on write
            abase2[i] = ((m / 21) * 25 + (m % 21)) * SH1_STRIDE;
        }
        f32x4 acc2[2][4];
        #pragma unroll
        for (int i = 0; i < 2; ++i)
            #pragma unroll
            for (int nt = 0; nt < 4; ++nt)
                acc2[i][nt] = (f32x4){0.f, 0.f, 0.f, 0.f};

        const unsigned short* wb = w2frag + lane * 8;
        bf16x8 bcur[4], acur[2];
        #pragma unroll
        for (int nt = 0; nt < 4; ++nt)
            bcur[nt] = *(const bf16x8*)(wb + nt * 512);
        #pragma unroll
        for (int i = 0; i < 2; ++i)
            acur[i] = *(const bf16x8*)(sbuf + abase2[i] + quad * 16);

        #pragma unroll
        for (int tap = 0; tap < 25; ++tap) {
            bf16x8 bnxt[4], anxt[2];
            if (tap < 24) {
                const int toff1 = (((tap + 1) / 5) * 25 + ((tap + 1) % 5)) * SH1_STRIDE;
                #pragma unroll
                for (int nt = 0; nt < 4; ++nt)
                    bnxt[nt] = *(const bf16x8*)(wb + ((tap + 1) * 4 + nt) * 512);
                #pragma unroll
                for (int i = 0; i < 2; ++i)
                    anxt[i] = *(const bf16x8*)(sbuf + abase2[i] + toff1 + quad * 16);  // b128
            }
            #pragma unroll
            for (int i = 0; i < 2; ++i)
                #pragma unroll
                for (int nt = 0; nt < 4; ++nt)
                    acc2[i][nt] = mfma_bf16(acur[i], bcur[nt], acc2[i][nt]);
            if (tap < 24) {
                #pragma unroll
                for (int nt = 0; nt < 4; ++nt) bcur[nt] = bnxt[nt];
                acur[0] = anxt[0]; acur[1] = anxt[1];
            }
        }
        // writeback: relu -> sH2 [pixel][60ch bf16]
        #pragma unroll
        for (int i = 0; i < 2; ++i) {
            #pragma unroll
            for (int r = 0; r < 4; ++r) {
                int pix = (wv + i * 14) * 16 + quad * 4 + r;
                if (pix < 441) {
                    unsigned short* rowp = (unsigned short*)(sbuf + SH2_BASE + pix * SH2_STRIDE);
                    #pragma unroll
                    for (int nt = 0; nt < 4; ++nt) {
                        int o = nt * 16 + ln15;
                        if (o < 60)
                            rowp[o] = f2bf(fmaxf(acc2[i][nt][r] + c2bias[nt], 0.f));
                    }
                }
            }
        }
    }
    __syncthreads();

    // ---- S3: deconv2 as MFMA. M=625(->640, 40 mtiles), N=32 (24+8 pad),
    //      K=64 (60+4 B-zero), 25 taps. Wave wv: mtiles {wv, wv+16, wv+32<40}.
    //      Depth-1 B prefetch: 12 MFMAs + 12 LDS reads stand between load
    //      issue and first use. ----
    f32x4 acc3[3][2];
    {
        #pragma unroll
        for (int i = 0; i < 3; ++i) {
            acc3[i][0] = (f32x4){0.f, 0.f, 0.f, 0.f};
            acc3[i][1] = (f32x4){0.f, 0.f, 0.f, 0.f};
        }
        int uarr[3], varr[3], a120[3];
        bool mval[3];
        #pragma unroll
        for (int i = 0; i < 3; ++i) {
            int m = (wv + i * 16) * 16 + ln15;
            mval[i] = (m < 625);
            int mc = mval[i] ? m : 0;
            uarr[i] = mc / 25; varr[i] = mc % 25;
            a120[i] = (uarr[i] * 21 + varr[i]) * SH2_STRIDE;
        }
        const unsigned short* db = dw2frag + lane * 8;
        bf16x8 bc[4];
        #pragma unroll
        for (int f = 0; f < 4; ++f)
            bc[f] = *(const bf16x8*)(db + f * 512);
        #pragma unroll
        for (int tap = 0; tap < 25; ++tap) {
            const int dy = tap / 5, dx = tap % 5;
            const int t2off = (dy * 21 + dx) * SH2_STRIDE;
            bf16x8 bn[4];
            if (tap < 24) {
                #pragma unroll
                for (int f = 0; f < 4; ++f)
                    bn[f] = *(const bf16x8*)(db + ((tap + 1) * 4 + f) * 512);
            }
            #pragma unroll
            for (int i = 0; i < 3; ++i) {
                if (i == 2 && wv >= 8) continue;       // wave-uniform skip
                int yv = uarr[i] - dy, xv = varr[i] - dx;
                bool ok = mval[i] && ((unsigned)yv < 21u) && ((unsigned)xv < 21u);
                int ra = ok ? (a120[i] - t2off) : ZROW_REL;  // zero row -> +0
                const char* ap = sbuf + SH2_BASE + ra + quad * 16;
                short4v lo0 = *(const short4v*)(ap);          // ds_read_b64
                short4v hi0 = *(const short4v*)(ap + 8);
                bf16x8 a0 = __builtin_shufflevector(lo0, hi0, 0, 1, 2, 3, 4, 5, 6, 7);
                acc3[i][0] = mfma_bf16(a0, bc[0], acc3[i][0]);
                acc3[i][1] = mfma_bf16(a0, bc[1], acc3[i][1]);
                short4v lo1 = *(const short4v*)(ap + 64);
                short4v hi1 = *(const short4v*)(ap + 72);
                bf16x8 a1 = __builtin_shufflevector(lo1, hi1, 0, 1, 2, 3, 4, 5, 6, 7);
                acc3[i][0] = mfma_bf16(a1, bc[2], acc3[i][0]);
                acc3[i][1] = mfma_bf16(a1, bc[3], acc3[i][1]);
            }
            if (tap < 24) {
                bc[0] = bn[0]; bc[1] = bn[1]; bc[2] = bn[2]; bc[3] = bn[3];
            }
        }
    }
    __syncthreads();   // sH1 & sH2 fully dead from here

    // ---- S4a: h3 = elu(acc3 + d2b) -> bf16 [625][24ch] stride 48B;
    //           build sWc (bf16, c>=24 zero); zero sp ----
    float* sp = (float*)(sbuf + SP_ACC);
    {
        const int c1ok = (16 + ln15 < 24);
        #pragma unroll
        for (int i = 0; i < 3; ++i) {
            if (i == 2 && wv >= 8) continue;
            #pragma unroll
            for (int r = 0; r < 4; ++r) {
                int pix = (wv + i * 16) * 16 + quad * 4 + r;
                if (pix < 625) {
                    unsigned short* rowp = (unsigned short*)(sbuf + pix * SH1_STRIDE);
                    float hv = acc3[i][0][r] + db0;
                    rowp[ln15] = f2bf(hv > 0.f ? hv : elu_neg(hv));
                    if (c1ok) {
                        float hw = acc3[i][1][r] + db1;
                        rowp[16 + ln15] = f2bf(hw > 0.f ? hw : elu_neg(hw));
                    }
                }
            }
        }
    }
    {   // sWc: 64 r x 32 c, stride 64B (dw1 gathers preloaded at top)
        int r0 = t >> 5, c0 = t & 31;
        ((unsigned short*)(sbuf + SWC_BASE))[r0 * 32 + c0] = f2bf(lw0 * dwp[0] + lw1 * dwp[1]);
        int k1 = t + 1024, r1 = k1 >> 5, c1 = k1 & 31;
        ((unsigned short*)(sbuf + SWC_BASE))[r1 * 32 + c1] = f2bf(lw0 * dwp[2] + lw1 * dwp[3]);
    }
    sp[t] = 0.f;
    __syncthreads();

    // ---- S4b: epilogue GEMM p[pix][r] = sum_c h3[pix][c]*wc[r][c] (K=32),
    //           scatter-add into sp via LDS atomics ----
    {
        bf16x8 wbv[4];
        #pragma unroll
        for (int nt = 0; nt < 4; ++nt)
            wbv[nt] = *(const bf16x8*)(sbuf + SWC_BASE + (nt * 16 + ln15) * 64 + quad * 16);
        #pragma unroll
        for (int i = 0; i < 3; ++i) {
            int mt = wv + i * 16;
            if (mt >= 40) continue;                 // wave-uniform
            int m = mt * 16 + ln15;
            if (m > 624) m = 624;
            bf16x8 a = *(const bf16x8*)(sbuf + m * SH1_STRIDE + quad * 16);  // b128
            #pragma unroll
            for (int nt = 0; nt < 4; ++nt) {
                f32x4 acc4 = (f32x4){0.f, 0.f, 0.f, 0.f};
                acc4 = mfma_bf16(a, wbv[nt], acc4);
                #pragma unroll
                for (int r = 0; r < 4; ++r) {
                    int pix = mt * 16 + quad * 4 + r;
                    if (pix < 625) {
                        int u = pix / 25, v = pix % 25;
                        int rv = nt * 16 + ln15;
                        atomicAdd(&sp[(u + (rv >> 3)) * 32 + v + (rv & 7)], acc4[r]);
                    }
                }
            }
        }
    }
    __syncthreads();

    // ---- S5: overlap-add into global recon ----
    const float obias = d1b0 * (lw0 + lw1) + lbn;
    {
        int yy = t >> 5, xx = t & 31;
        atomicAdd(&recon[(Y0 + yy) * W_ + (X0 + xx)], sp[t] + obias);
    }
}

// ---------------------------------------------------------------------------
// Prep (layouts unchanged from R4):
//  conv1:   i = (kc*2+nt)*512 + lane*8 + j -> n=nt*16+(lane&15), k=kc*32+(lane>>4)*8+j
//  conv2:   tap*2048 + nt*512 + lane*8 + j -> o=nt*16+ln15, c=quad*8+j (zeros o>=60, c>=24)
//  deconv2: tap*2048 + kc*1024 + nt*512 + lane*8 + j -> k=kc*32+quad*8+j, c=nt*16+ln15
//           (zeros k>=60, c>=24)
// ---------------------------------------------------------------------------
__global__ void prep_kernel(const float* __restrict__ c1w,
                            const float* __restrict__ c2w,
                            const float* __restrict__ d2w,
                            unsigned short* __restrict__ w1frag,
                            unsigned short* __restrict__ w2frag,
                            unsigned short* __restrict__ dw2frag)
{
    int i = blockIdx.x * blockDim.x + threadIdx.x;
    if (i < 51200) {
        int j = i & 7, lane = (i >> 3) & 63;
        int ln15 = lane & 15, quad = lane >> 4;
        if (i < 4096) {   // conv1
            int g = i >> 9;                   // = kc*2 + nt
            int kc = g >> 1, nt = g & 1;
            int nn = nt * 16 + ln15, k = kc * 32 + quad * 8 + j;
            w1frag[i] = f2bf((nn < 24) ? c1w[nn * 128 + k] : 0.f);
        }
        {   // conv2
            int nt = (i >> 9) & 3, tap = i >> 11;
            int o = nt * 16 + ln15, c = quad * 8 + j;
            float v = (o < 60 && c < 24) ? c2w[(o * 24 + c) * 25 + tap] : 0.f;
            w2frag[i] = f2bf(v);
        }
        {   // deconv2
            int nt = (i >> 9) & 1, kc = (i >> 10) & 1, tap = i >> 11;
            int k = kc * 32 + quad * 8 + j, c = nt * 16 + ln15;
            float v = (k < 60 && c < 24) ? d2w[(k * 24 + c) * 25 + tap] : 0.f;
            dw2frag[i] = f2bf(v);
        }
    }
}

__global__ void finalize_kernel(const float* __restrict__ x2,
                                const float* __restrict__ l1w,
                                float* __restrict__ out)
{
    int i = blockIdx.x * blockDim.x + threadIdx.x;
    if (i < H_ * W_) {
        float r = out[i];
        out[i] = x2[i] - r * l1w[0];
    }
}

extern "C" void kernel_launch(void* const* d_in, const int* in_sizes, int n_in,
                              void* d_out, int out_size, void* d_ws, size_t ws_size,
                              hipStream_t stream)
{
    const float* x1  = (const float*)d_in[0];
    const float* x2  = (const float*)d_in[1];
    const float* c1w = (const float*)d_in[2];
    const float* c1b = (const float*)d_in[3];
    const float* c2w = (const float*)d_in[4];
    const float* c2b = (const float*)d_in[5];
    const float* d2w = (const float*)d_in[6];
    const float* d2b = (const float*)d_in[7];
    const float* d1w = (const float*)d_in[8];
    const float* d1b = (const float*)d_in[9];
    const float* lw  = (const float*)d_in[10];
    const float* lb  = (const float*)d_in[11];
    const float* l1w = (const float*)d_in[12];

    float*          out     = (float*)d_out;
    unsigned short* w1frag  = (unsigned short*)d_ws;                      // 8192 B
    unsigned short* w2frag  = (unsigned short*)((char*)d_ws + 8192);      // 102400 B
    unsigned short* dw2frag = (unsigned short*)((char*)d_ws + 110592);    // 102400 B

    hipMemsetAsync(d_out, 0, (size_t)H_ * W_ * sizeof(float), stream);
    prep_kernel<<<100, 512, 0, stream>>>(c1w, c2w, d2w, w1frag, w2frag, dw2frag);
    fused_patch_kernel<<<NPATCH_, 1024, 0, stream>>>(x1, x2, c1b, c2b, d2b, d1b,
                                                     lw, lb, w1frag, w2frag, dw2frag,
                                                     d1w, out);
    finalize_kernel<<<(H_ * W_ + 255) / 256, 256, 0, stream>>>(x2, l1w, out);
}